// Round 11
// baseline (156.434 us; speedup 1.0000x reference)
//
#include <hip/hip_runtime.h>

// SecurePooling: x (32,1000,14,14) f32 -> pred (32,) int32
// Even-coordinate SAT S[r][c] = sum(x[0:2r,0:2c]), r,c in 0..7 is a complete
// sufficient statistic. 351 streams per b: 325 unordered pairs (two[p][q]),
// 25 one-mask, 1 total.  Argmax over c per stream, first-index tie-break.
//
// R11: R9's verified phases + kernC fused via per-b LAST-BLOCK pattern
// (device-scope atomicAdd + threadfence; no cooperative launch -> graph-
// capture-safe; no dispatch-order or co-residency assumption, G16-clean).
//   P0: stage 64 raw images (49 KB) into LDS, coalesced float4.
//   P1: 64 threads compute even-SAT IN-PLACE in lx.
//   P2: W[c][27] = {w[25], total, 0};  LT[c][27] = {total-w[25], total, -}.
//   P3: lane = stream, serial argmax over 64 c's -> part[b][wc][sid].
//   P4: the LAST-finished block of each b merges 16 chunks + decides out[b].

#define NC 1000
#define NCH 16      // c-chunks of 64 (chunk 15 overlaps: c0=936)
#define PSTRIDE 384
#define PART_BYTES ((size_t)32 * NCH * PSTRIDE * 8)   // 1.57 MB

__host__ __device__ constexpr int tri_off(int p) { return p * 25 - p * (p - 1) / 2; }

__global__ __launch_bounds__(384) void fused(const float* __restrict__ x,
                                             unsigned long long* __restrict__ part,
                                             int* __restrict__ cnt,
                                             int* __restrict__ out) {
    __shared__ float lx[64 * 197];                       // images; later SAT overlay
    __shared__ float W[64][27];                          // {w[25], total, 0}
    __shared__ float LT[64][27];                         // {total-w[25], total, -}
    __shared__ unsigned long long mg[352];               // P4 merge buffer
    __shared__ int is_last;
    const int tid = threadIdx.x;
    const int b = blockIdx.x >> 4;
    const int wc = blockIdx.x & 15;
    const int c0 = (wc == 15) ? 936 : wc * 64;           // chunk 15 overlaps 14
    const int cl = tid & 63;
    const int hi = tid >> 6;                             // 0..5

    // ---- P0: stage 64 images = 3136 float4, coalesced ----
    const float4* x4 = reinterpret_cast<const float4*>(x)
                       + (size_t)(b * NC + c0) * 49;
#pragma unroll
    for (int it = 0; it < 9; ++it) {
        const int f = it * 384 + tid;
        if (f < 3136) {
            float4 v = x4[f];
            const int img = f / 49;
            const int off = f - img * 49;
            float* d = &lx[img * 197 + off * 4];
            d[0] = v.x; d[1] = v.y; d[2] = v.z; d[3] = v.w;
        }
    }
    __syncthreads();

    // ---- P1: in-place even SAT per image (identical arithmetic to R9) ----
    if (tid < 64) {
        float* row = &lx[tid * 197];
        float colacc[7];
#pragma unroll
        for (int c = 0; c < 7; ++c) colacc[c] = 0.f;
#pragma unroll
        for (int r = 0; r < 7; ++r) {
            float rowf[28];
#pragma unroll
            for (int j = 0; j < 28; ++j) rowf[j] = row[r * 28 + j];
            if (r == 0) {
#pragma unroll
                for (int j = 0; j < 8; ++j) row[j] = 0.f;    // S row 0
            }
            row[(r + 1) * 8] = 0.f;                          // S[r+1][0]
            float run = 0.f;
#pragma unroll
            for (int c = 0; c < 7; ++c) {
                const float blk2 = rowf[2 * c] + rowf[2 * c + 1]
                                 + rowf[14 + 2 * c] + rowf[14 + 2 * c + 1];
                colacc[c] += blk2;
                run += colacc[c];
                row[(r + 1) * 8 + c + 1] = run;
            }
        }
    }
    __syncthreads();

    // ---- P2: W/LT tables (R2 FP order for w; LT = total - w hoisted) ----
#define SC(c, k) lx[(c) * 197 + (k)]
    {
        const float total = SC(cl, 63);
#pragma unroll
        for (int j = hi; j < 27; j += 6) {
            float wv, ltv;
            if (j < 25) {
                const int p1 = j / 5, p2 = j % 5;
                wv = ((SC(cl, (p1 + 3) * 8 + p2 + 3) - SC(cl, p1 * 8 + p2 + 3))
                      - SC(cl, (p1 + 3) * 8 + p2)) + SC(cl, p1 * 8 + p2);
                ltv = total - wv;
            } else if (j == 25) {
                wv = total; ltv = total;
            } else {
                wv = 0.f; ltv = total;
            }
            W[cl][j] = wv;
            LT[cl][j] = ltv;
        }
    }
    __syncthreads();

    // ---- P3: lane = stream sid (0..350 active) ----
    const int sid = tid;
    if (sid < 351) {
        int pi, qi, i0, i1, i2, i3;
        if (sid < 325) {
            int p = 0;
            while (tri_off(p + 1) <= sid) ++p;           // once, <=24 iters
            const int q = p + (sid - tri_off(p));
            const int p1 = p / 5, p2 = p % 5, q1 = q / 5, q2 = q % 5;
            const int rlo = (p1 > q1 ? p1 : q1);
            const int rmn = (p1 < q1 ? p1 : q1);
            const int rhi = (rmn + 3 > rlo ? rmn + 3 : rlo);
            const int clo = (p2 > q2 ? p2 : q2);
            const int cmn = (p2 < q2 ? p2 : q2);
            const int chi = (cmn + 3 > clo ? cmn + 3 : clo);
            pi = p; qi = q;
            i0 = rhi * 8 + chi; i1 = rlo * 8 + chi;
            i2 = rhi * 8 + clo; i3 = rlo * 8 + clo;
        } else if (sid < 350) {
            pi = sid - 325; qi = 26;                     // W[c][26]=0
            i0 = i1 = i2 = i3 = 0;                       // SC(c,0)=0 -> rect=0
        } else {
            pi = 25; qi = 26; i0 = i1 = i2 = i3 = 0;     // total stream
        }
        // v = (LT[c][pi] - W[c][qi]) + (((S[i0]-S[i1]) - S[i2]) + S[i3])
        float bv = -3.4e38f;
        int bc = 0;
#pragma unroll 4
        for (int c = 0; c < 64; ++c) {
            const float rect = ((SC(c, i0) - SC(c, i1)) - SC(c, i2)) + SC(c, i3);
            const float v = (LT[c][pi] - W[c][qi]) + rect;
            if (v > bv) { bv = v; bc = c; }              // strict >: first-index
        }
        const unsigned u = __float_as_uint(bv);
        const unsigned fk = u ^ (unsigned)(((int)u >> 31) | 0x80000000);
        part[(size_t)(b * NCH + wc) * PSTRIDE + sid] =
            ((unsigned long long)fk << 32) | (unsigned)~(unsigned)(c0 + bc);
    }
#undef SC

    // ---- last-block handoff (device-scope; no ordering assumptions) ----
    __threadfence();                                     // release part slice
    if (tid == 0)
        is_last = (atomicAdd(&cnt[b], 1) == NCH - 1);
    __syncthreads();
    if (!is_last) return;
    __threadfence();                                     // acquire all slices

    // ---- P4: merge 16 chunks + final decision (one block per b) ----
    if (tid < 351) {
        unsigned long long m = 0ull;
#pragma unroll
        for (int ch = 0; ch < NCH; ++ch) {
            unsigned long long v = part[(size_t)(b * NCH + ch) * PSTRIDE + tid];
            if (v > m) m = v;
        }
        mg[tid] = m;
    }
    __syncthreads();
    if (tid < 64) {
        const unsigned predidx = (unsigned)mg[350];
        const int pred = (int)~predidx;
        bool cand = false;
        int p1 = 0;
        if (tid < 25) {
            const unsigned p1i = (unsigned)mg[325 + tid];
            p1 = (int)~p1i;
            bool ag = true;
            for (int j = 0; j < 25; ++j) {
                const int a = tid < j ? tid : j;
                const int q = tid < j ? j : tid;
                ag = ag && ((unsigned)mg[tri_off(a) + (q - a)] == p1i);
            }
            cand = ag && (p1 != pred);
        }
        const unsigned long long mask = __ballot(cand);
        int ans = pred;
        if (mask) ans = __shfl(p1, __ffsll(mask) - 1, 64);
        if (tid == 0) out[b] = ans;
    }
}

extern "C" void kernel_launch(void* const* d_in, const int* in_sizes, int n_in,
                              void* d_out, int out_size, void* d_ws, size_t ws_size,
                              hipStream_t stream) {
    const float* x = (const float*)d_in[0];
    int* out = (int*)d_out;
    unsigned long long* part = (unsigned long long*)d_ws;        // 1.57 MB
    int* cnt = (int*)((char*)d_ws + PART_BYTES);                 // 32 ints

    hipMemsetAsync(cnt, 0, 32 * sizeof(int), stream);            // capture-safe
    fused<<<32 * NCH, 384, 0, stream>>>(x, part, cnt, out);
}